// Round 7
// baseline (218.945 us; speedup 1.0000x reference)
//
#include <hip/hip_runtime.h>
#include <hip/hip_bf16.h>

#define KN  2048   // nodes
#define KD  256    // emb dim = HF
#define KH  4      // heads
#define KF  64     // feat/head
#define KT  64     // time steps
#define NCS 32     // colsum partial buffers

typedef __attribute__((ext_vector_type(8))) short short8;
typedef __attribute__((ext_vector_type(4))) float floatx4;

// ---------------- helpers ----------------
__device__ __forceinline__ float wave_sum(float v) {
    #pragma unroll
    for (int o = 32; o > 0; o >>= 1) v += __shfl_xor(v, o, 64);
    return v;
}
__device__ __forceinline__ float wave_max(float v) {
    #pragma unroll
    for (int o = 32; o > 0; o >>= 1) v = fmaxf(v, __shfl_xor(v, o, 64));
    return v;
}
__device__ __forceinline__ short f2bs(float x) {
    union { __hip_bfloat16 h; short s; } u;
    u.h = __float2bfloat16(x);
    return u.s;
}

// ---------------- corr body: 64x64 tile, 4x4/thread, f32 ----------------
// Normalization fused: thread (r=t>>2, q=t&3) preloads row r's 16 values
// (k = c*16 + q*4 + u), quad-shfl reduces mean/sumsq, normalizes in-register,
// then stages chunks exactly as the proven round-2..6 pipeline.
__device__ __forceinline__ void corr_body(const float* __restrict__ y,
                                          const float* __restrict__ adj,
                                          unsigned char* __restrict__ code,
                                          int blk, char* smem) {
    float (*As)[68] = (float(*)[68])smem;            // 16x68 f32
    float (*Bs)[68] = (float(*)[68])(smem + 4352);
    int t = threadIdx.x;
    int tx = t & 15, ty = t >> 4;
    int j0 = (blk & 31) * 64, i0 = (blk >> 5) * 64;
    int r = t >> 2, q = t & 3;
    float4 ai[4], bj[4];
    #pragma unroll
    for (int c = 0; c < 4; c++) {
        ai[c] = *reinterpret_cast<const float4*>(&y[(size_t)(i0 + r) * KT + c * 16 + q * 4]);
        bj[c] = *reinterpret_cast<const float4*>(&y[(size_t)(j0 + r) * KT + c * 16 + q * 4]);
    }
    float sa = 0.0f, sa2 = 0.0f, sb = 0.0f, sb2 = 0.0f;
    #pragma unroll
    for (int c = 0; c < 4; c++) {
        float av[4] = {ai[c].x, ai[c].y, ai[c].z, ai[c].w};
        float bv[4] = {bj[c].x, bj[c].y, bj[c].z, bj[c].w};
        #pragma unroll
        for (int u = 0; u < 4; u++) {
            sa += av[u]; sa2 += av[u] * av[u];
            sb += bv[u]; sb2 += bv[u] * bv[u];
        }
    }
    #pragma unroll
    for (int o = 1; o < 4; o <<= 1) {
        sa += __shfl_xor(sa, o, 64);  sa2 += __shfl_xor(sa2, o, 64);
        sb += __shfl_xor(sb, o, 64);  sb2 += __shfl_xor(sb2, o, 64);
    }
    float ma = sa * (1.0f / KT), mb = sb * (1.0f / KT);
    float inva = rsqrtf((sa2 - KT * ma * ma) * (1.0f / (KT - 1)));
    float invb = rsqrtf((sb2 - KT * mb * mb) * (1.0f / (KT - 1)));
    #pragma unroll
    for (int c = 0; c < 4; c++) {
        ai[c].x = (ai[c].x - ma) * inva; ai[c].y = (ai[c].y - ma) * inva;
        ai[c].z = (ai[c].z - ma) * inva; ai[c].w = (ai[c].w - ma) * inva;
        bj[c].x = (bj[c].x - mb) * invb; bj[c].y = (bj[c].y - mb) * invb;
        bj[c].z = (bj[c].z - mb) * invb; bj[c].w = (bj[c].w - mb) * invb;
    }
    float acc[4][4] = {};
    #pragma unroll
    for (int c = 0; c < 4; c++) {
        As[q * 4 + 0][r] = ai[c].x; As[q * 4 + 1][r] = ai[c].y;
        As[q * 4 + 2][r] = ai[c].z; As[q * 4 + 3][r] = ai[c].w;
        Bs[q * 4 + 0][r] = bj[c].x; Bs[q * 4 + 1][r] = bj[c].y;
        Bs[q * 4 + 2][r] = bj[c].z; Bs[q * 4 + 3][r] = bj[c].w;
        __syncthreads();
        #pragma unroll
        for (int kk = 0; kk < 16; kk++) {
            float4 av4 = *reinterpret_cast<const float4*>(&As[kk][ty * 4]);
            float4 bv4 = *reinterpret_cast<const float4*>(&Bs[kk][tx * 4]);
            float a4v[4] = {av4.x, av4.y, av4.z, av4.w};
            float b4v[4] = {bv4.x, bv4.y, bv4.z, bv4.w};
            #pragma unroll
            for (int ii = 0; ii < 4; ii++)
                #pragma unroll
                for (int jj = 0; jj < 4; jj++) acc[ii][jj] += a4v[ii] * b4v[jj];
        }
        __syncthreads();
    }
    #pragma unroll
    for (int ii = 0; ii < 4; ii++) {
        int i = i0 + ty * 4 + ii;
        int jb = j0 + tx * 4;
        float4 av4 = *reinterpret_cast<const float4*>(&adj[(size_t)i * KN + jb]);
        float a4v[4] = {av4.x, av4.y, av4.z, av4.w};
        uchar4 cc;
        unsigned char* c = (unsigned char*)&cc;
        #pragma unroll
        for (int jj = 0; jj < 4; jj++)
            c[jj] = (a4v[jj] != 0.0f) ? ((acc[ii][jj] >= 0.1f) ? 1 : 2) : 0;
        *reinterpret_cast<uchar4*>(&code[(size_t)i * KN + jb]) = cc;
    }
}

// ---------------- MFMA bf16 GEMM body: 64x64 C tile, K=256 ----------------
// A f32 [M,256] row-major, B f32 [256,*] row-major (tile at bn), C f32.
// bias pre-offset to the 64-entry tile slice (or null). Optional fused f1/f2
// head reduction (f1h/f2h pre-offset by h*KN; wu_h/wv_h head 64-entry slice).
template <bool TANH>
__device__ __forceinline__ void mfma_gemm_body(
    const float* __restrict__ A, int lda, int bm,
    const float* __restrict__ B, int ldb, int bn,
    const float* __restrict__ bias,
    float* __restrict__ C, int ldc, int cn,
    float* __restrict__ f1h, float* __restrict__ f2h,
    const float* __restrict__ wu_h, const float* __restrict__ wv_h,
    char* smem)
{
    short* As = (short*)smem;            // [64][40] bf16 (row m, col k)
    short* Bs = (short*)(smem + 5120);   // [64][40] bf16 (row n, col k) transposed
    int t = threadIdx.x;
    int w = t >> 6, lane = t & 63;
    int m16 = lane & 15, kq = lane >> 4;
    floatx4 acc0 = {0,0,0,0}, acc1 = {0,0,0,0}, acc2 = {0,0,0,0}, acc3 = {0,0,0,0};
    int ar = t >> 2, acq = (t & 3) * 8;     // A stage: row 0..63, k-offset {0,8,16,24}
    int bnn = t & 63, bkg = (t >> 6) * 8;   // B stage: col 0..63, k-group {0,8,16,24}
    for (int kt = 0; kt < KD; kt += 32) {
        const float* pa = &A[(size_t)(bm + ar) * lda + kt + acq];
        float4 a0 = *(const float4*)pa;
        float4 a1 = *(const float4*)(pa + 4);
        short8 av;
        av[0] = f2bs(a0.x); av[1] = f2bs(a0.y); av[2] = f2bs(a0.z); av[3] = f2bs(a0.w);
        av[4] = f2bs(a1.x); av[5] = f2bs(a1.y); av[6] = f2bs(a1.z); av[7] = f2bs(a1.w);
        const float* pb = &B[(size_t)(kt + bkg) * ldb + bn + bnn];
        short8 bv;
        #pragma unroll
        for (int u = 0; u < 8; u++) bv[u] = f2bs(pb[(size_t)u * ldb]);
        __syncthreads();   // previous iteration's frag reads complete
        *(short8*)&As[ar * 40 + acq] = av;
        *(short8*)&Bs[bnn * 40 + bkg] = bv;
        __syncthreads();
        short8 af  = *(short8*)&As[(w * 16 + m16) * 40 + kq * 8];
        short8 bf0 = *(short8*)&Bs[( 0 + m16) * 40 + kq * 8];
        short8 bf1 = *(short8*)&Bs[(16 + m16) * 40 + kq * 8];
        short8 bf2 = *(short8*)&Bs[(32 + m16) * 40 + kq * 8];
        short8 bf3 = *(short8*)&Bs[(48 + m16) * 40 + kq * 8];
        acc0 = __builtin_amdgcn_mfma_f32_16x16x32_bf16(af, bf0, acc0, 0, 0, 0);
        acc1 = __builtin_amdgcn_mfma_f32_16x16x32_bf16(af, bf1, acc1, 0, 0, 0);
        acc2 = __builtin_amdgcn_mfma_f32_16x16x32_bf16(af, bf2, acc2, 0, 0, 0);
        acc3 = __builtin_amdgcn_mfma_f32_16x16x32_bf16(af, bf3, acc3, 0, 0, 0);
    }
    // epilogue: C/D layout col=lane&15, row=(lane>>4)*4+reg
    int row0 = bm + w * 16 + kq * 4;
    floatx4 accs[4] = {acc0, acc1, acc2, acc3};
    #pragma unroll
    for (int nb = 0; nb < 4; nb++) {
        #pragma unroll
        for (int r = 0; r < 4; r++) {
            int col = nb * 16 + m16;
            float v = accs[nb][r] + (bias ? bias[col] : 0.0f);
            if (TANH) {
                float vc = fminf(fmaxf(v, -9.0f), 9.0f);
                float ex = __expf(2.0f * vc);
                v = (ex - 1.0f) / (ex + 1.0f);
            }
            C[(size_t)(row0 + r) * ldc + cn + col] = v;
        }
    }
    if (f1h) {  // fused f1/f2: dot each row with wu/wv over this head's 64 cols
        float wuv[4], wvv[4];
        #pragma unroll
        for (int nb = 0; nb < 4; nb++) { wuv[nb] = wu_h[nb * 16 + m16]; wvv[nb] = wv_h[nb * 16 + m16]; }
        #pragma unroll
        for (int r = 0; r < 4; r++) {
            float p1 = accs[0][r] * wuv[0] + accs[1][r] * wuv[1] + accs[2][r] * wuv[2] + accs[3][r] * wuv[3];
            float p2 = accs[0][r] * wvv[0] + accs[1][r] * wvv[1] + accs[2][r] * wvv[2] + accs[3][r] * wvv[3];
            #pragma unroll
            for (int o = 1; o < 16; o <<= 1) {
                p1 += __shfl_xor(p1, o, 64);
                p2 += __shfl_xor(p2, o, 64);
            }
            if (m16 == 0) { f1h[row0 + r] = p1; f2h[row0 + r] = p2; }
        }
    }
}

// ---------------- K1: phase1 = corr (1024) + emb GEMM (640) + colsum zero --
struct EmbPtrs {
    float *S_pos, *S_neg, *P_pos, *P_neg, *sup;
    float *f1p, *f2p, *f1n, *f2n;
};
__global__ __launch_bounds__(256) void phase1_kernel(
    const float* __restrict__ y, const float* __restrict__ adj,
    unsigned char* __restrict__ code,
    const float* __restrict__ emb,
    const float* __restrict__ pos_w, const float* __restrict__ neg_w,
    const float* __restrict__ pos_pw, const float* __restrict__ neg_pw,
    const float* __restrict__ self_w,
    const float* __restrict__ pos_pb, const float* __restrict__ neg_pb,
    const float* __restrict__ self_b,
    const float* __restrict__ pos_wu, const float* __restrict__ pos_wv,
    const float* __restrict__ neg_wu, const float* __restrict__ neg_wv,
    float* __restrict__ colsum, EmbPtrs ep)
{
    __shared__ alignas(16) char smem[10240];
    int blk = blockIdx.x;
    if (blk < 1024) {
        corr_body(y, adj, code, blk, smem);
        return;
    }
    if (blk >= 1664) {   // colsum zero
        for (int j = threadIdx.x; j < NCS * KD; j += 256) colsum[j] = 0.0f;
        return;
    }
    int b = blk - 1024;            // 0..639
    int tn = b % 20, tm = b / 20;
    int buf = tn >> 2, coloff = (tn & 3) * 64;
    int h = tn & 3;
    const float* B; const float* bias; float* C;
    float *f1h = nullptr, *f2h = nullptr;
    const float *wu_h = nullptr, *wv_h = nullptr;
    if (buf == 0) {
        B = pos_w;  bias = nullptr; C = ep.S_pos;
        f1h = ep.f1p + h * KN; f2h = ep.f2p + h * KN;
        wu_h = pos_wu + h * KF; wv_h = pos_wv + h * KF;
    } else if (buf == 1) {
        B = neg_w;  bias = nullptr; C = ep.S_neg;
        f1h = ep.f1n + h * KN; f2h = ep.f2n + h * KN;
        wu_h = neg_wu + h * KF; wv_h = neg_wv + h * KF;
    } else if (buf == 2) { B = pos_pw; bias = pos_pb + coloff;  C = ep.P_pos; }
    else if (buf == 3)   { B = neg_pw; bias = neg_pb + coloff;  C = ep.P_neg; }
    else                 { B = self_w; bias = self_b + coloff;  C = ep.sup; }
    mfma_gemm_body<false>(emb, KD, tm * 64, B, KD, coloff, bias,
                          C, KD, coloff, f1h, f2h, wu_h, wv_h, smem);
}

// K2: [G_pos;G_neg](4096x256) @ {mlp_pos|mlp_neg} -> [psup;nsup], plus
//     T0 = tanh(sup @ sem_w1 + sem_b1) on blocks by>=64
__global__ __launch_bounds__(256) void gemm_mlp(const float* __restrict__ Astack,
                                                const float* __restrict__ B0,
                                                const float* __restrict__ B1,
                                                const float* __restrict__ b0,
                                                const float* __restrict__ b1,
                                                float* __restrict__ Cstack,
                                                const float* __restrict__ sup,
                                                const float* __restrict__ semw1,
                                                const float* __restrict__ semb1,
                                                float* __restrict__ T0) {
    __shared__ alignas(16) char smem[10240];
    int by = blockIdx.y;
    int cn = blockIdx.x * 64;
    if (by < 64) {
        int bm = by * 64;
        bool sel = bm >= KN;
        mfma_gemm_body<false>(Astack, KD, bm, sel ? B1 : B0, KD, cn,
                              (sel ? b1 : b0) + cn, Cstack, KD, cn,
                              nullptr, nullptr, nullptr, nullptr, smem);
    } else {
        int bm = (by - 64) * 64;
        mfma_gemm_body<true>(sup, KD, bm, semw1, KD, cn,
                             semb1 + cn, T0, KD, cn,
                             nullptr, nullptr, nullptr, nullptr, smem);
    }
}

// K3: [psup;nsup](4096x256) @ sem_w1 + b, tanh -> [T1;T2]
__global__ __launch_bounds__(256) void gemm_sem(const float* __restrict__ Astack,
                                                const float* __restrict__ B,
                                                const float* __restrict__ bias,
                                                float* __restrict__ Cstack) {
    __shared__ alignas(16) char smem[10240];
    int cn = blockIdx.x * 64;
    mfma_gemm_body<true>(Astack, KD, blockIdx.y * 64, B, KD, cn,
                         bias + cn, Cstack, KD, cn,
                         nullptr, nullptr, nullptr, nullptr, smem);
}

// ---------------- K4: sparse GAT row, block per (i,rel), wave = head ------
#define MAXE 256
__global__ __launch_bounds__(256) void attn_kernel(
    const unsigned char* __restrict__ code,
    const float* __restrict__ f1p, const float* __restrict__ f2p,
    const float* __restrict__ Sp, const float* __restrict__ Pp,
    const float* __restrict__ bp, float* __restrict__ Gp,
    const float* __restrict__ f1n, const float* __restrict__ f2n,
    const float* __restrict__ Sn, const float* __restrict__ Pn,
    const float* __restrict__ bn_, float* __restrict__ Gn)
{
    __shared__ alignas(16) int jl[MAXE];
    __shared__ alignas(16) float lg[KH][MAXE];
    __shared__ int cnt;
    int blk = blockIdx.x;
    int rel = blk >> 11;
    int i = blk & (KN - 1);
    unsigned char want = rel ? (unsigned char)2 : (unsigned char)1;
    const float* f1 = rel ? f1n : f1p;
    const float* f2 = rel ? f2n : f2p;
    const float* S  = rel ? Sn : Sp;
    const float* P  = rel ? Pn : Pp;
    const float* b  = rel ? bn_ : bp;
    float* G        = rel ? Gn : Gp;
    int w = threadIdx.x >> 6, lane = threadIdx.x & 63;
    if (threadIdx.x == 0) cnt = 0;
    __syncthreads();
    // cooperative scan: wave w covers columns [w*512, w*512+512)
    #pragma unroll
    for (int it = 0; it < 2; it++) {
        int base = w * 512 + it * 256;
        uchar4 cv = *reinterpret_cast<const uchar4*>(&code[(size_t)i * KN + base + lane * 4]);
        const unsigned char* ce = (const unsigned char*)&cv;
        #pragma unroll
        for (int e = 0; e < 4; e++) {
            bool p = (ce[e] == want);
            unsigned long long bal = __ballot(p);
            int tot = __popcll(bal);
            int basepos = 0;
            if (lane == 0 && tot) basepos = atomicAdd(&cnt, tot);
            basepos = __shfl(basepos, 0, 64);
            if (p) {
                int idx = basepos + __popcll(bal & ((1ull << lane) - 1ull));
                if (idx < MAXE) jl[idx] = base + lane * 4 + e;
            }
        }
    }
    __syncthreads();
    int count = cnt; if (count > MAXE) count = MAXE;
    int countR = (count + 3) & ~3;
    if (threadIdx.x < countR - count) jl[count + threadIdx.x] = 0;  // pad: valid idx, zero weight later
    __syncthreads();
    int h = w;                                  // one wave per head
    float f2i = f2[h * KN + i];
    float m = -1e30f;
    for (int k = lane; k < count; k += 64) {
        int j = jl[k];
        float x = f1[h * KN + j] + f2i;
        x = (x > 0.0f) ? x : 0.2f * x;          // leaky_relu 0.2
        lg[h][k] = x;
        m = fmaxf(m, x);
    }
    m = wave_max(m);
    float ps = 0.0f;
    for (int k = lane; k < count; k += 64) {
        float e = __expf(lg[h][k] - m);
        lg[h][k] = e;
        ps += e;
    }
    float denom = wave_sum(ps);
    for (int k2 = count + lane; k2 < countR; k2 += 64) lg[h][k2] = 0.0f;  // own-wave pad
    // gather: 16 lanes x float4 per j, 4 j's per iteration
    int g = lane >> 4, q4 = (lane & 15) * 4;
    const float* Sh4 = S + h * KF + q4;
    float ax = 0.0f, ay = 0.0f, az = 0.0f, aw = 0.0f;
    for (int k = 0; k < countR; k += 4) {
        int j = jl[k + g];
        float wgt = lg[h][k + g];
        float4 sv = *reinterpret_cast<const float4*>(&Sh4[(size_t)j * KD]);
        ax += wgt * sv.x; ay += wgt * sv.y; az += wgt * sv.z; aw += wgt * sv.w;
    }
    #pragma unroll
    for (int o = 16; o < 64; o <<= 1) {
        ax += __shfl_xor(ax, o, 64); ay += __shfl_xor(ay, o, 64);
        az += __shfl_xor(az, o, 64); aw += __shfl_xor(aw, o, 64);
    }
    if (g == 0) {
        float inv = count ? (1.0f / denom) : 0.0f;
        int col = h * KF + q4;
        size_t idx = (size_t)i * KD + col;
        float4 pv = *reinterpret_cast<const float4*>(&P[idx]);
        float4 o4;
        o4.x = ax * inv + b[col + 0] + pv.x;
        o4.y = ay * inv + b[col + 1] + pv.y;
        o4.z = az * inv + b[col + 2] + pv.z;
        o4.w = aw * inv + b[col + 3] + pv.w;
        *reinterpret_cast<float4*>(&G[idx]) = o4;
    }
}

// ---------------- K5: semantic attention blend + colsum partials --------
__global__ __launch_bounds__(256) void combine_kernel(const float* __restrict__ T0,
                                                      const float* __restrict__ T1,
                                                      const float* __restrict__ T2,
                                                      const float* __restrict__ w2,
                                                      const float* __restrict__ sup,
                                                      const float* __restrict__ psup,
                                                      const float* __restrict__ nsup,
                                                      float* __restrict__ X,
                                                      float* __restrict__ colsum) {
    int n = blockIdx.x, d = threadIdx.x;
    size_t idx = (size_t)n * KD + d;
    float w2d = w2[d];
    float p0 = T0[idx] * w2d, p1 = T1[idx] * w2d, p2 = T2[idx] * w2d;
    __shared__ float sbuf[4][3];
    int wv = d >> 6, lane = d & 63;
    float s0 = wave_sum(p0), s1 = wave_sum(p1), s2 = wave_sum(p2);
    if (lane == 0) { sbuf[wv][0] = s0; sbuf[wv][1] = s1; sbuf[wv][2] = s2; }
    __syncthreads();
    float w0 = sbuf[0][0] + sbuf[1][0] + sbuf[2][0] + sbuf[3][0];
    float w1 = sbuf[0][1] + sbuf[1][1] + sbuf[2][1] + sbuf[3][1];
    float w2l = sbuf[0][2] + sbuf[1][2] + sbuf[2][2] + sbuf[3][2];
    float mm = fmaxf(w0, fmaxf(w1, w2l));
    float e0 = __expf(w0 - mm), e1 = __expf(w1 - mm), e2 = __expf(w2l - mm);
    float inv = 1.0f / (e0 + e1 + e2);
    float x = (e0 * inv) * sup[idx] + (e1 * inv) * psup[idx] + (e2 * inv) * nsup[idx];
    X[idx] = x;
    atomicAdd(&colsum[(n & (NCS - 1)) * KD + d], x);
}

// ---------------- K6: PairNorm PN-SI + store ----------------
__global__ __launch_bounds__(256) void final_kernel(const float* __restrict__ X,
                                                    const float* __restrict__ colsum,
                                                    float* __restrict__ out) {
    int n = blockIdx.x, d = threadIdx.x;
    float cs = 0.0f;
    #pragma unroll
    for (int r = 0; r < NCS; r++) cs += colsum[r * KD + d];
    float mean = cs * (1.0f / KN);
    float xc = X[(size_t)n * KD + d] - mean;
    __shared__ float sbuf[4];
    int wv = d >> 6, lane = d & 63;
    float s = wave_sum(xc * xc);
    if (lane == 0) sbuf[wv] = s;
    __syncthreads();
    float ss = sbuf[0] + sbuf[1] + sbuf[2] + sbuf[3];
    out[(size_t)n * KD + d] = xc * rsqrtf(1e-6f + ss);
}

// ---------------- host ----------------
extern "C" void kernel_launch(void* const* d_in, const int* in_sizes, int n_in,
                              void* d_out, int out_size, void* d_ws, size_t ws_size,
                              hipStream_t stream) {
    typedef const float* fp;
    fp emb    = (fp)d_in[0];
    fp y_as_x = (fp)d_in[1];
    fp adj    = (fp)d_in[2];
    fp pos_w  = (fp)d_in[3],  pos_wu = (fp)d_in[4],  pos_wv = (fp)d_in[5];
    fp pos_b  = (fp)d_in[6],  pos_pw = (fp)d_in[7],  pos_pb = (fp)d_in[8];
    fp neg_w  = (fp)d_in[9],  neg_wu = (fp)d_in[10], neg_wv = (fp)d_in[11];
    fp neg_b  = (fp)d_in[12], neg_pw = (fp)d_in[13], neg_pb = (fp)d_in[14];
    fp self_w = (fp)d_in[15], self_b = (fp)d_in[16];
    fp mlp_pos_w = (fp)d_in[17], mlp_pos_b = (fp)d_in[18];
    fp mlp_neg_w = (fp)d_in[19], mlp_neg_b = (fp)d_in[20];
    fp sem_w1 = (fp)d_in[21], sem_b1 = (fp)d_in[22], sem_w2 = (fp)d_in[23];
    float* out = (float*)d_out;

    char* ws = (char*)d_ws;
    unsigned char* cd = (unsigned char*)(ws + 0x0080000);  // 4 MB
    float* S_pos      = (float*)(ws + 0x0480000);          // 2 MB each
    float* S_neg      = (float*)(ws + 0x0680000);
    float* P_pos      = (float*)(ws + 0x0880000);          // later T0
    float* P_neg      = (float*)(ws + 0x0A80000);          // later T1
    float* G_pos      = (float*)(ws + 0x0C80000);          // later T2 (G_pos|G_neg contiguous)
    float* G_neg      = (float*)(ws + 0x0E80000);          // later X
    float* sup        = (float*)(ws + 0x1080000);          // sup|psup|nsup contiguous
    float* psup       = (float*)(ws + 0x1280000);          // psup|nsup = mlp C stack
    float* nsup       = (float*)(ws + 0x1480000);
    float* colsum     = (float*)(ws + 0x1680000);          // 32 KB
    float* f1p        = (float*)(ws + 0x1700000);          // 32 KB each
    float* f2p        = (float*)(ws + 0x1708000);
    float* f1n        = (float*)(ws + 0x1710000);
    float* f2n        = (float*)(ws + 0x1718000);
    float* T0 = P_pos, *T1 = P_neg, *T2 = G_pos, *X = G_neg;

    EmbPtrs ep = {S_pos, S_neg, P_pos, P_neg, sup, f1p, f2p, f1n, f2n};
    phase1_kernel<<<1024 + 640 + 1, 256, 0, stream>>>(y_as_x, adj, cd, emb,
                                                      pos_w, neg_w, pos_pw, neg_pw, self_w,
                                                      pos_pb, neg_pb, self_b,
                                                      pos_wu, pos_wv, neg_wu, neg_wv,
                                                      colsum, ep);

    attn_kernel<<<2 * KN, 256, 0, stream>>>(cd,
                                            f1p, f2p, S_pos, P_pos, pos_b, G_pos,
                                            f1n, f2n, S_neg, P_neg, neg_b, G_neg);

    gemm_mlp<<<dim3(4, 96), 256, 0, stream>>>(G_pos, mlp_pos_w, mlp_neg_w,
                                              mlp_pos_b, mlp_neg_b, psup,
                                              sup, sem_w1, sem_b1, T0);
    gemm_sem<<<dim3(4, 64), 256, 0, stream>>>(psup, sem_w1, sem_b1, T1);

    combine_kernel<<<KN, 256, 0, stream>>>(T0, T1, T2, sem_w2, sup, psup, nsup, X, colsum);
    final_kernel<<<KN, 256, 0, stream>>>(X, colsum, out);
}

// Round 8
// 169.542 us; speedup vs baseline: 1.2914x; 1.2914x over previous
//
#include <hip/hip_runtime.h>
#include <hip/hip_bf16.h>

#define KN  2048   // nodes
#define KD  256    // emb dim = HF
#define KH  4      // heads
#define KF  64     // feat/head
#define KT  64     // time steps
#define NCS 32     // colsum partial buffers

typedef __attribute__((ext_vector_type(8))) short short8;
typedef __attribute__((ext_vector_type(4))) float floatx4;

// ---------------- helpers ----------------
__device__ __forceinline__ float wave_sum(float v) {
    #pragma unroll
    for (int o = 32; o > 0; o >>= 1) v += __shfl_xor(v, o, 64);
    return v;
}
__device__ __forceinline__ float wave_max(float v) {
    #pragma unroll
    for (int o = 32; o > 0; o >>= 1) v = fmaxf(v, __shfl_xor(v, o, 64));
    return v;
}
__device__ __forceinline__ short f2bs(float x) {
    union { __hip_bfloat16 h; short s; } u;
    u.h = __float2bfloat16(x);
    return u.s;
}

// ---------------- K0: setup = ycs normalize ----------------
__global__ __launch_bounds__(256) void setup_kernel(const float* __restrict__ y,
                                                    float* __restrict__ ycs) {
    int w = threadIdx.x >> 6, lane = threadIdx.x & 63;
    int n = blockIdx.x * 4 + w;
    float v = y[n * KT + lane];
    float mean = wave_sum(v) * (1.0f / KT);
    float yc = v - mean;
    float ss = wave_sum(yc * yc);
    ycs[n * KT + lane] = yc * rsqrtf(ss * (1.0f / (KT - 1)));
}

// ---------------- corr body: upper-tri 64x64 tile, writes (i,j) AND (j,i) --
__device__ __forceinline__ void corr_body(const float* __restrict__ ycs,
                                          const float* __restrict__ adj,
                                          unsigned char* __restrict__ code,
                                          int blk, char* smem) {
    float (*As)[68] = (float(*)[68])smem;            // 16x68 f32
    float (*Bs)[68] = (float(*)[68])(smem + 4352);
    // triangular decode: blk -> (bi, bj), bi <= bj, 32x32 block grid
    int bi = 0, rem = blk;
    while (rem >= 32 - bi) { rem -= 32 - bi; bi++; }
    int bj = bi + rem;
    int i0 = bi * 64, j0 = bj * 64;
    int t = threadIdx.x;
    int tx = t & 15, ty = t >> 4;
    int ar = t >> 2, ac = (t & 3) * 4;
    float acc[4][4] = {};
    for (int kt = 0; kt < KT; kt += 16) {
        float4 a4 = *reinterpret_cast<const float4*>(&ycs[(size_t)(i0 + ar) * KT + kt + ac]);
        float4 b4 = *reinterpret_cast<const float4*>(&ycs[(size_t)(j0 + ar) * KT + kt + ac]);
        As[ac + 0][ar] = a4.x; As[ac + 1][ar] = a4.y; As[ac + 2][ar] = a4.z; As[ac + 3][ar] = a4.w;
        Bs[ac + 0][ar] = b4.x; Bs[ac + 1][ar] = b4.y; Bs[ac + 2][ar] = b4.z; Bs[ac + 3][ar] = b4.w;
        __syncthreads();
        #pragma unroll
        for (int kk = 0; kk < 16; kk++) {
            float4 av = *reinterpret_cast<const float4*>(&As[kk][ty * 4]);
            float4 bv = *reinterpret_cast<const float4*>(&Bs[kk][tx * 4]);
            float a4v[4] = {av.x, av.y, av.z, av.w};
            float b4v[4] = {bv.x, bv.y, bv.z, bv.w};
            #pragma unroll
            for (int ii = 0; ii < 4; ii++)
                #pragma unroll
                for (int jj = 0; jj < 4; jj++) acc[ii][jj] += a4v[ii] * b4v[jj];
        }
        __syncthreads();
    }
    // write code[i][j] from adj[i][j]
    #pragma unroll
    for (int ii = 0; ii < 4; ii++) {
        int i = i0 + ty * 4 + ii;
        int jb = j0 + tx * 4;
        float4 av4 = *reinterpret_cast<const float4*>(&adj[(size_t)i * KN + jb]);
        float a4v[4] = {av4.x, av4.y, av4.z, av4.w};
        uchar4 cc;
        unsigned char* c = (unsigned char*)&cc;
        #pragma unroll
        for (int jj = 0; jj < 4; jj++)
            c[jj] = (a4v[jj] != 0.0f) ? ((acc[ii][jj] >= 0.1f) ? 1 : 2) : 0;
        *reinterpret_cast<uchar4*>(&code[(size_t)i * KN + jb]) = cc;
    }
    // write code[j][i] from adj[j][i] (corr symmetric), skip diagonal blocks
    if (bi != bj) {
        #pragma unroll
        for (int jj = 0; jj < 4; jj++) {
            int j = j0 + tx * 4 + jj;
            int ib = i0 + ty * 4;
            float4 av4 = *reinterpret_cast<const float4*>(&adj[(size_t)j * KN + ib]);
            float a4v[4] = {av4.x, av4.y, av4.z, av4.w};
            uchar4 cc;
            unsigned char* c = (unsigned char*)&cc;
            #pragma unroll
            for (int ii = 0; ii < 4; ii++)
                c[ii] = (a4v[ii] != 0.0f) ? ((acc[ii][jj] >= 0.1f) ? 1 : 2) : 0;
            *reinterpret_cast<uchar4*>(&code[(size_t)j * KN + ib]) = cc;
        }
    }
}

// ---------------- MFMA bf16 GEMM body: 64x64 C tile, K=256 ----------------
// A f32 [M,256] row-major, B f32 [256,*] row-major (tile at bn), C f32.
// bias pre-offset to the 64-entry tile slice (or null). Optional fused f1/f2
// head reduction (f1h/f2h pre-offset by h*KN; wu_h/wv_h head 64-entry slice).
template <bool TANH>
__device__ __forceinline__ void mfma_gemm_body(
    const float* __restrict__ A, int lda, int bm,
    const float* __restrict__ B, int ldb, int bn,
    const float* __restrict__ bias,
    float* __restrict__ C, int ldc, int cn,
    float* __restrict__ f1h, float* __restrict__ f2h,
    const float* __restrict__ wu_h, const float* __restrict__ wv_h,
    char* smem)
{
    short* As = (short*)smem;            // [64][40] bf16 (row m, col k)
    short* Bs = (short*)(smem + 5120);   // [64][40] bf16 (row n, col k) transposed
    int t = threadIdx.x;
    int w = t >> 6, lane = t & 63;
    int m16 = lane & 15, kq = lane >> 4;
    floatx4 acc0 = {0,0,0,0}, acc1 = {0,0,0,0}, acc2 = {0,0,0,0}, acc3 = {0,0,0,0};
    int ar = t >> 2, acq = (t & 3) * 8;     // A stage: row 0..63, k-offset {0,8,16,24}
    int bnn = t & 63, bkg = (t >> 6) * 8;   // B stage: col 0..63, k-group {0,8,16,24}
    for (int kt = 0; kt < KD; kt += 32) {
        const float* pa = &A[(size_t)(bm + ar) * lda + kt + acq];
        float4 a0 = *(const float4*)pa;
        float4 a1 = *(const float4*)(pa + 4);
        short8 av;
        av[0] = f2bs(a0.x); av[1] = f2bs(a0.y); av[2] = f2bs(a0.z); av[3] = f2bs(a0.w);
        av[4] = f2bs(a1.x); av[5] = f2bs(a1.y); av[6] = f2bs(a1.z); av[7] = f2bs(a1.w);
        const float* pb = &B[(size_t)(kt + bkg) * ldb + bn + bnn];
        short8 bv;
        #pragma unroll
        for (int u = 0; u < 8; u++) bv[u] = f2bs(pb[(size_t)u * ldb]);
        __syncthreads();   // previous iteration's frag reads complete
        *(short8*)&As[ar * 40 + acq] = av;
        *(short8*)&Bs[bnn * 40 + bkg] = bv;
        __syncthreads();
        short8 af  = *(short8*)&As[(w * 16 + m16) * 40 + kq * 8];
        short8 bf0 = *(short8*)&Bs[( 0 + m16) * 40 + kq * 8];
        short8 bf1 = *(short8*)&Bs[(16 + m16) * 40 + kq * 8];
        short8 bf2 = *(short8*)&Bs[(32 + m16) * 40 + kq * 8];
        short8 bf3 = *(short8*)&Bs[(48 + m16) * 40 + kq * 8];
        acc0 = __builtin_amdgcn_mfma_f32_16x16x32_bf16(af, bf0, acc0, 0, 0, 0);
        acc1 = __builtin_amdgcn_mfma_f32_16x16x32_bf16(af, bf1, acc1, 0, 0, 0);
        acc2 = __builtin_amdgcn_mfma_f32_16x16x32_bf16(af, bf2, acc2, 0, 0, 0);
        acc3 = __builtin_amdgcn_mfma_f32_16x16x32_bf16(af, bf3, acc3, 0, 0, 0);
    }
    // epilogue: C/D layout col=lane&15, row=(lane>>4)*4+reg
    int row0 = bm + w * 16 + kq * 4;
    floatx4 accs[4] = {acc0, acc1, acc2, acc3};
    #pragma unroll
    for (int nb = 0; nb < 4; nb++) {
        #pragma unroll
        for (int r = 0; r < 4; r++) {
            int col = nb * 16 + m16;
            float v = accs[nb][r] + (bias ? bias[col] : 0.0f);
            if (TANH) {
                float vc = fminf(fmaxf(v, -9.0f), 9.0f);
                float ex = __expf(2.0f * vc);
                v = (ex - 1.0f) / (ex + 1.0f);
            }
            C[(size_t)(row0 + r) * ldc + cn + col] = v;
        }
    }
    if (f1h) {  // fused f1/f2: dot each row with wu/wv over this head's 64 cols
        float wuv[4], wvv[4];
        #pragma unroll
        for (int nb = 0; nb < 4; nb++) { wuv[nb] = wu_h[nb * 16 + m16]; wvv[nb] = wv_h[nb * 16 + m16]; }
        #pragma unroll
        for (int r = 0; r < 4; r++) {
            float p1 = accs[0][r] * wuv[0] + accs[1][r] * wuv[1] + accs[2][r] * wuv[2] + accs[3][r] * wuv[3];
            float p2 = accs[0][r] * wvv[0] + accs[1][r] * wvv[1] + accs[2][r] * wvv[2] + accs[3][r] * wvv[3];
            #pragma unroll
            for (int o = 1; o < 16; o <<= 1) {
                p1 += __shfl_xor(p1, o, 64);
                p2 += __shfl_xor(p2, o, 64);
            }
            if (m16 == 0) { f1h[row0 + r] = p1; f2h[row0 + r] = p2; }
        }
    }
}

// ---- K1: phase1 = corr upper-tri (528) + emb GEMM (640) + colsum zero (1) --
struct EmbPtrs {
    float *S_pos, *S_neg, *P_pos, *P_neg, *sup;
    float *f1p, *f2p, *f1n, *f2n;
};
__global__ __launch_bounds__(256, 4) void phase1_kernel(
    const float* __restrict__ ycs, const float* __restrict__ adj,
    unsigned char* __restrict__ code,
    const float* __restrict__ emb,
    const float* __restrict__ pos_w, const float* __restrict__ neg_w,
    const float* __restrict__ pos_pw, const float* __restrict__ neg_pw,
    const float* __restrict__ self_w,
    const float* __restrict__ pos_pb, const float* __restrict__ neg_pb,
    const float* __restrict__ self_b,
    const float* __restrict__ pos_wu, const float* __restrict__ pos_wv,
    const float* __restrict__ neg_wu, const float* __restrict__ neg_wv,
    float* __restrict__ colsum, EmbPtrs ep)
{
    __shared__ alignas(16) char smem[10240];
    int blk = blockIdx.x;
    if (blk < 528) {
        corr_body(ycs, adj, code, blk, smem);
        return;
    }
    if (blk >= 1168) {   // colsum zero
        for (int j = threadIdx.x; j < NCS * KD; j += 256) colsum[j] = 0.0f;
        return;
    }
    int b = blk - 528;             // 0..639
    int tn = b % 20, tm = b / 20;
    int buf = tn >> 2, coloff = (tn & 3) * 64;
    int h = tn & 3;
    const float* B; const float* bias; float* C;
    float *f1h = nullptr, *f2h = nullptr;
    const float *wu_h = nullptr, *wv_h = nullptr;
    if (buf == 0) {
        B = pos_w;  bias = nullptr; C = ep.S_pos;
        f1h = ep.f1p + h * KN; f2h = ep.f2p + h * KN;
        wu_h = pos_wu + h * KF; wv_h = pos_wv + h * KF;
    } else if (buf == 1) {
        B = neg_w;  bias = nullptr; C = ep.S_neg;
        f1h = ep.f1n + h * KN; f2h = ep.f2n + h * KN;
        wu_h = neg_wu + h * KF; wv_h = neg_wv + h * KF;
    } else if (buf == 2) { B = pos_pw; bias = pos_pb + coloff;  C = ep.P_pos; }
    else if (buf == 3)   { B = neg_pw; bias = neg_pb + coloff;  C = ep.P_neg; }
    else                 { B = self_w; bias = self_b + coloff;  C = ep.sup; }
    mfma_gemm_body<false>(emb, KD, tm * 64, B, KD, coloff, bias,
                          C, KD, coloff, f1h, f2h, wu_h, wv_h, smem);
}

// K2: [G_pos;G_neg](4096x256) @ {mlp_pos|mlp_neg} -> [psup;nsup], plus
//     T0 = tanh(sup @ sem_w1 + sem_b1) on blocks by>=64
__global__ __launch_bounds__(256, 4) void gemm_mlp(const float* __restrict__ Astack,
                                                   const float* __restrict__ B0,
                                                   const float* __restrict__ B1,
                                                   const float* __restrict__ b0,
                                                   const float* __restrict__ b1,
                                                   float* __restrict__ Cstack,
                                                   const float* __restrict__ sup,
                                                   const float* __restrict__ semw1,
                                                   const float* __restrict__ semb1,
                                                   float* __restrict__ T0) {
    __shared__ alignas(16) char smem[10240];
    int by = blockIdx.y;
    int cn = blockIdx.x * 64;
    if (by < 64) {
        int bm = by * 64;
        bool sel = bm >= KN;
        mfma_gemm_body<false>(Astack, KD, bm, sel ? B1 : B0, KD, cn,
                              (sel ? b1 : b0) + cn, Cstack, KD, cn,
                              nullptr, nullptr, nullptr, nullptr, smem);
    } else {
        int bm = (by - 64) * 64;
        mfma_gemm_body<true>(sup, KD, bm, semw1, KD, cn,
                             semb1 + cn, T0, KD, cn,
                             nullptr, nullptr, nullptr, nullptr, smem);
    }
}

// K3: [psup;nsup](4096x256) @ sem_w1 + b, tanh -> [T1;T2]
__global__ __launch_bounds__(256, 4) void gemm_sem(const float* __restrict__ Astack,
                                                   const float* __restrict__ B,
                                                   const float* __restrict__ bias,
                                                   float* __restrict__ Cstack) {
    __shared__ alignas(16) char smem[10240];
    int cn = blockIdx.x * 64;
    mfma_gemm_body<true>(Astack, KD, blockIdx.y * 64, B, KD, cn,
                         bias + cn, Cstack, KD, cn,
                         nullptr, nullptr, nullptr, nullptr, smem);
}

// ---------------- K4: sparse GAT row, block per (i,rel), wave = head ------
#define MAXE 256
__global__ __launch_bounds__(256) void attn_kernel(
    const unsigned char* __restrict__ code,
    const float* __restrict__ f1p, const float* __restrict__ f2p,
    const float* __restrict__ Sp, const float* __restrict__ Pp,
    const float* __restrict__ bp, float* __restrict__ Gp,
    const float* __restrict__ f1n, const float* __restrict__ f2n,
    const float* __restrict__ Sn, const float* __restrict__ Pn,
    const float* __restrict__ bn_, float* __restrict__ Gn)
{
    __shared__ alignas(16) int jl[MAXE];
    __shared__ alignas(16) float lg[KH][MAXE];
    __shared__ int cnt;
    int blk = blockIdx.x;
    int rel = blk >> 11;
    int i = blk & (KN - 1);
    unsigned char want = rel ? (unsigned char)2 : (unsigned char)1;
    const float* f1 = rel ? f1n : f1p;
    const float* f2 = rel ? f2n : f2p;
    const float* S  = rel ? Sn : Sp;
    const float* P  = rel ? Pn : Pp;
    const float* b  = rel ? bn_ : bp;
    float* G        = rel ? Gn : Gp;
    int w = threadIdx.x >> 6, lane = threadIdx.x & 63;
    if (threadIdx.x == 0) cnt = 0;
    __syncthreads();
    // cooperative scan: wave w covers columns [w*512, w*512+512)
    #pragma unroll
    for (int it = 0; it < 2; it++) {
        int base = w * 512 + it * 256;
        uchar4 cv = *reinterpret_cast<const uchar4*>(&code[(size_t)i * KN + base + lane * 4]);
        const unsigned char* ce = (const unsigned char*)&cv;
        #pragma unroll
        for (int e = 0; e < 4; e++) {
            bool p = (ce[e] == want);
            unsigned long long bal = __ballot(p);
            int tot = __popcll(bal);
            int basepos = 0;
            if (lane == 0 && tot) basepos = atomicAdd(&cnt, tot);
            basepos = __shfl(basepos, 0, 64);
            if (p) {
                int idx = basepos + __popcll(bal & ((1ull << lane) - 1ull));
                if (idx < MAXE) jl[idx] = base + lane * 4 + e;
            }
        }
    }
    __syncthreads();
    int count = cnt; if (count > MAXE) count = MAXE;
    int countR = (count + 3) & ~3;
    if (threadIdx.x < countR - count) jl[count + threadIdx.x] = 0;  // pad: valid idx, zero weight later
    __syncthreads();
    int h = w;                                  // one wave per head
    float f2i = f2[h * KN + i];
    float m = -1e30f;
    for (int k = lane; k < count; k += 64) {
        int j = jl[k];
        float x = f1[h * KN + j] + f2i;
        x = (x > 0.0f) ? x : 0.2f * x;          // leaky_relu 0.2
        lg[h][k] = x;
        m = fmaxf(m, x);
    }
    m = wave_max(m);
    float ps = 0.0f;
    for (int k = lane; k < count; k += 64) {
        float e = __expf(lg[h][k] - m);
        lg[h][k] = e;
        ps += e;
    }
    float denom = wave_sum(ps);
    for (int k2 = count + lane; k2 < countR; k2 += 64) lg[h][k2] = 0.0f;  // own-wave pad
    // gather: 16 lanes x float4 per j, 4 j's per iteration
    int g = lane >> 4, q4 = (lane & 15) * 4;
    const float* Sh4 = S + h * KF + q4;
    float ax = 0.0f, ay = 0.0f, az = 0.0f, aw = 0.0f;
    for (int k = 0; k < countR; k += 4) {
        int j = jl[k + g];
        float wgt = lg[h][k + g];
        float4 sv = *reinterpret_cast<const float4*>(&Sh4[(size_t)j * KD]);
        ax += wgt * sv.x; ay += wgt * sv.y; az += wgt * sv.z; aw += wgt * sv.w;
    }
    #pragma unroll
    for (int o = 16; o < 64; o <<= 1) {
        ax += __shfl_xor(ax, o, 64); ay += __shfl_xor(ay, o, 64);
        az += __shfl_xor(az, o, 64); aw += __shfl_xor(aw, o, 64);
    }
    if (g == 0) {
        float inv = count ? (1.0f / denom) : 0.0f;
        int col = h * KF + q4;
        size_t idx = (size_t)i * KD + col;
        float4 pv = *reinterpret_cast<const float4*>(&P[idx]);
        float4 o4;
        o4.x = ax * inv + b[col + 0] + pv.x;
        o4.y = ay * inv + b[col + 1] + pv.y;
        o4.z = az * inv + b[col + 2] + pv.z;
        o4.w = aw * inv + b[col + 3] + pv.w;
        *reinterpret_cast<float4*>(&G[idx]) = o4;
    }
}

// ---------------- K5: semantic attention blend + colsum partials --------
__global__ __launch_bounds__(256) void combine_kernel(const float* __restrict__ T0,
                                                      const float* __restrict__ T1,
                                                      const float* __restrict__ T2,
                                                      const float* __restrict__ w2,
                                                      const float* __restrict__ sup,
                                                      const float* __restrict__ psup,
                                                      const float* __restrict__ nsup,
                                                      float* __restrict__ X,
                                                      float* __restrict__ colsum) {
    int n = blockIdx.x, d = threadIdx.x;
    size_t idx = (size_t)n * KD + d;
    float w2d = w2[d];
    float p0 = T0[idx] * w2d, p1 = T1[idx] * w2d, p2 = T2[idx] * w2d;
    __shared__ float sbuf[4][3];
    int wv = d >> 6, lane = d & 63;
    float s0 = wave_sum(p0), s1 = wave_sum(p1), s2 = wave_sum(p2);
    if (lane == 0) { sbuf[wv][0] = s0; sbuf[wv][1] = s1; sbuf[wv][2] = s2; }
    __syncthreads();
    float w0 = sbuf[0][0] + sbuf[1][0] + sbuf[2][0] + sbuf[3][0];
    float w1 = sbuf[0][1] + sbuf[1][1] + sbuf[2][1] + sbuf[3][1];
    float w2l = sbuf[0][2] + sbuf[1][2] + sbuf[2][2] + sbuf[3][2];
    float mm = fmaxf(w0, fmaxf(w1, w2l));
    float e0 = __expf(w0 - mm), e1 = __expf(w1 - mm), e2 = __expf(w2l - mm);
    float inv = 1.0f / (e0 + e1 + e2);
    float x = (e0 * inv) * sup[idx] + (e1 * inv) * psup[idx] + (e2 * inv) * nsup[idx];
    X[idx] = x;
    atomicAdd(&colsum[(n & (NCS - 1)) * KD + d], x);
}

// ---------------- K6: PairNorm PN-SI + store ----------------
__global__ __launch_bounds__(256) void final_kernel(const float* __restrict__ X,
                                                    const float* __restrict__ colsum,
                                                    float* __restrict__ out) {
    int n = blockIdx.x, d = threadIdx.x;
    float cs = 0.0f;
    #pragma unroll
    for (int r = 0; r < NCS; r++) cs += colsum[r * KD + d];
    float mean = cs * (1.0f / KN);
    float xc = X[(size_t)n * KD + d] - mean;
    __shared__ float sbuf[4];
    int wv = d >> 6, lane = d & 63;
    float s = wave_sum(xc * xc);
    if (lane == 0) sbuf[wv] = s;
    __syncthreads();
    float ss = sbuf[0] + sbuf[1] + sbuf[2] + sbuf[3];
    out[(size_t)n * KD + d] = xc * rsqrtf(1e-6f + ss);
}

// ---------------- host ----------------
extern "C" void kernel_launch(void* const* d_in, const int* in_sizes, int n_in,
                              void* d_out, int out_size, void* d_ws, size_t ws_size,
                              hipStream_t stream) {
    typedef const float* fp;
    fp emb    = (fp)d_in[0];
    fp y_as_x = (fp)d_in[1];
    fp adj    = (fp)d_in[2];
    fp pos_w  = (fp)d_in[3],  pos_wu = (fp)d_in[4],  pos_wv = (fp)d_in[5];
    fp pos_b  = (fp)d_in[6],  pos_pw = (fp)d_in[7],  pos_pb = (fp)d_in[8];
    fp neg_w  = (fp)d_in[9],  neg_wu = (fp)d_in[10], neg_wv = (fp)d_in[11];
    fp neg_b  = (fp)d_in[12], neg_pw = (fp)d_in[13], neg_pb = (fp)d_in[14];
    fp self_w = (fp)d_in[15], self_b = (fp)d_in[16];
    fp mlp_pos_w = (fp)d_in[17], mlp_pos_b = (fp)d_in[18];
    fp mlp_neg_w = (fp)d_in[19], mlp_neg_b = (fp)d_in[20];
    fp sem_w1 = (fp)d_in[21], sem_b1 = (fp)d_in[22], sem_w2 = (fp)d_in[23];
    float* out = (float*)d_out;

    char* ws = (char*)d_ws;
    float* ycs        = (float*)(ws + 0x0000000);          // 512 KB
    unsigned char* cd = (unsigned char*)(ws + 0x0080000);  // 4 MB
    float* S_pos      = (float*)(ws + 0x0480000);          // 2 MB each
    float* S_neg      = (float*)(ws + 0x0680000);
    float* P_pos      = (float*)(ws + 0x0880000);          // later T0
    float* P_neg      = (float*)(ws + 0x0A80000);          // later T1
    float* G_pos      = (float*)(ws + 0x0C80000);          // later T2 (G_pos|G_neg contiguous)
    float* G_neg      = (float*)(ws + 0x0E80000);          // later X
    float* sup        = (float*)(ws + 0x1080000);          // sup|psup|nsup contiguous
    float* psup       = (float*)(ws + 0x1280000);          // psup|nsup = mlp C stack
    float* nsup       = (float*)(ws + 0x1480000);
    float* colsum     = (float*)(ws + 0x1680000);          // 32 KB
    float* f1p        = (float*)(ws + 0x1700000);          // 32 KB each
    float* f2p        = (float*)(ws + 0x1708000);
    float* f1n        = (float*)(ws + 0x1710000);
    float* f2n        = (float*)(ws + 0x1718000);
    float* T0 = P_pos, *T1 = P_neg, *T2 = G_pos, *X = G_neg;

    setup_kernel<<<512, 256, 0, stream>>>(y_as_x, ycs);

    EmbPtrs ep = {S_pos, S_neg, P_pos, P_neg, sup, f1p, f2p, f1n, f2n};
    phase1_kernel<<<528 + 640 + 1, 256, 0, stream>>>(ycs, adj, cd, emb,
                                                     pos_w, neg_w, pos_pw, neg_pw, self_w,
                                                     pos_pb, neg_pb, self_b,
                                                     pos_wu, pos_wv, neg_wu, neg_wv,
                                                     colsum, ep);

    attn_kernel<<<2 * KN, 256, 0, stream>>>(cd,
                                            f1p, f2p, S_pos, P_pos, pos_b, G_pos,
                                            f1n, f2n, S_neg, P_neg, neg_b, G_neg);

    gemm_mlp<<<dim3(4, 96), 256, 0, stream>>>(G_pos, mlp_pos_w, mlp_neg_w,
                                              mlp_pos_b, mlp_neg_b, psup,
                                              sup, sem_w1, sem_b1, T0);
    gemm_sem<<<dim3(4, 64), 256, 0, stream>>>(psup, sem_w1, sem_b1, T1);

    combine_kernel<<<KN, 256, 0, stream>>>(T0, T1, T2, sem_w2, sup, psup, nsup, X, colsum);
    final_kernel<<<KN, 256, 0, stream>>>(X, colsum, out);
}